// Round 5
// baseline (171.327 us; speedup 1.0000x reference)
//
#include <hip/hip_runtime.h>

#define HD  64      // HIDDEN_DIM
#define NE  512     // N_EMBEDS
#define HW  1024    // 32*32 spatial positions per batch image

// ---------------------------------------------------------------------------
// Prep kernel (72 blocks x 64 threads):
//  blocks 0..63 : pack octet o: ep[o][c][j] = -2 * e[o*8+j][c]   (o = k>>3)
//                 -2 fold is bit-exact: pow2 scaling commutes with fp32
//                 rounding, so main's d = (xsq+esq) + a == (xsq+esq) - 2a.
//  blocks 64..71: esq[k] = np.sum(e[k]*e[k]) with numpy's pairwise-8 order,
//                 no contraction. Verified absmax == 0.0 in R1-R4.
// ---------------------------------------------------------------------------
__global__ __launch_bounds__(64) void vq_prep_kernel(const float* __restrict__ e,
                                                     float* __restrict__ ep,
                                                     float* __restrict__ esq) {
  const int blk = blockIdx.x;
  if (blk < 64) {
    const int c = threadIdx.x;                  // 0..63
    #pragma unroll
    for (int j = 0; j < 8; ++j) {
      ep[blk * 512 + c * 8 + j] = -2.0f * e[(blk * 8 + j) * HD + c];
    }
  } else {
    const int k = (blk - 64) * 64 + threadIdx.x;  // 0..511
    const float4* __restrict__ rowv = reinterpret_cast<const float4*>(e + k * HD);
    float row[HD];
    #pragma unroll
    for (int i = 0; i < 16; ++i) {
      const float4 v = rowv[i];
      row[4 * i + 0] = v.x; row[4 * i + 1] = v.y;
      row[4 * i + 2] = v.z; row[4 * i + 3] = v.w;
    }
    float result;
    {
      #pragma clang fp contract(off)
      float r[8];
      #pragma unroll
      for (int j = 0; j < 8; ++j) r[j] = row[j] * row[j];
      #pragma unroll
      for (int i = 8; i < HD; i += 8) {
        #pragma unroll
        for (int j = 0; j < 8; ++j) r[j] = r[j] + row[i + j] * row[i + j];
      }
      result = ((r[0] + r[1]) + (r[2] + r[3])) + ((r[4] + r[5]) + (r[6] + r[7]));
    }
    esq[k] = result;
  }
}

// ---------------------------------------------------------------------------
// Main kernel R5: 1024 blocks x 512 threads (8 waves). Block = 64 positions
// (lane = position); wave w covers codes [w*64, w*64+64) = octets
// [w*8, w*8+8).
//
//  - x in LDS xs[c][lane]: stride-1 conflict-free ds_read_b32, removes the
//    xv[64]-in-VGPR fight (R2/R3: allocator refused, VGPR stuck at 52).
//  - e via the SCALAR pipe: po is wave-uniform (readfirstlane) so po[c*8+j]
//    becomes s_load; FMA is v_fmac_f32 acc, sgpr, vgpr -- e costs zero VALU
//    ops and zero VGPRs. This is what R4's float4 e-path got wrong (40+ live
//    VGPRs under a 64 cap -> 95 MB scratch spill traffic).
//  - Register demand ~25 VGPRs -> (512,8) cap of 64 is roomy; 1024 blocks x
//    8 waves = 32 waves/CU, grid-limited full occupancy.
// ---------------------------------------------------------------------------
__global__ __launch_bounds__(512, 8) void vq_main_kernel(const float* __restrict__ x,
                                                         const float* __restrict__ ep,
                                                         const float* __restrict__ esq,
                                                         const float* __restrict__ e,
                                                         float* __restrict__ out) {
  __shared__ float xs[64 * 64];     // [c][lane]  16 KB
  __shared__ float smin[8][64];
  __shared__ int   sidx[8][64];
  __shared__ int   bcomb[64];

  const int t    = threadIdx.x;
  const int lane = t & 63;
  const int w    = t >> 6;                       // 0..7
  const int blk  = blockIdx.x;                   // 1024 blocks
  const int b    = blk >> 4;                     // batch
  const int s0   = (blk & 15) << 6;              // spatial chunk base
  const size_t xbase = (size_t)b * (HD * HW) + s0;

  // ---- stage x into LDS: wave w loads c in [w*8, w*8+8), lanes sweep pos
  #pragma unroll
  for (int i = 0; i < 8; ++i) {
    const int c = w * 8 + i;
    xs[(c << 6) | lane] = x[xbase + (size_t)c * HW + lane];
  }
  __syncthreads();

  // ---- x_sq with numpy pairwise-8 order, no contraction (same values as
  // global, routed through LDS -- bit-identical)
  float xsq;
  {
    #pragma clang fp contract(off)
    float r[8];
    #pragma unroll
    for (int j = 0; j < 8; ++j) {
      const float v = xs[(j << 6) | lane];
      r[j] = v * v;
    }
    #pragma unroll
    for (int i = 8; i < HD; i += 8) {
      #pragma unroll
      for (int j = 0; j < 8; ++j) {
        const float v = xs[((i + j) << 6) | lane];
        r[j] = r[j] + v * v;
      }
    }
    xsq = ((r[0] + r[1]) + (r[2] + r[3])) + ((r[4] + r[5]) + (r[6] + r[7]));
  }

  // ---- this wave scans octets [w*8, w*8+8)  (codes [w*64, w*64+64))
  const int o0 = __builtin_amdgcn_readfirstlane(w) * 8;

  float bestd = __builtin_inff();
  int   besti = 0;
  #pragma unroll 1
  for (int o = o0; o < o0 + 8; ++o) {
    // wave-uniform base -> all po[] accesses are scalar (s_load) operands
    const float* __restrict__ po = ep + (size_t)o * 512;
    float a[8];
    #pragma unroll
    for (int j = 0; j < 8; ++j) a[j] = 0.f;
    #pragma unroll
    for (int c = 0; c < HD; ++c) {
      const float xc = xs[(c << 6) | lane];
      #pragma unroll
      for (int j = 0; j < 8; ++j)
        a[j] = fmaf(xc, po[c * 8 + j], a[j]);   // v_fmac acc, sgpr, vgpr
    }
    const int kb = o * 8;
    #pragma unroll
    for (int j = 0; j < 8; ++j) {
      const float d = (xsq + esq[kb + j]) + a[j];  // == (xsq+esq) - 2*cross, bit-exact
      if (d < bestd) { bestd = d; besti = kb + j; } // strict < : first-index-wins
    }
  }

  // ---- combine the 8 waves' candidates per position (waves are ascending
  // k-ranges; strict < keeps the earlier wave on ties -> first-index-wins)
  smin[w][lane] = bestd;
  sidx[w][lane] = besti;
  __syncthreads();
  if (w == 0) {
    float bd = smin[0][lane];
    int   bi = sidx[0][lane];
    #pragma unroll
    for (int q = 1; q < 8; ++q) {
      const float d = smin[q][lane];
      if (d < bd) { bd = d; bi = sidx[q][lane]; }
    }
    bcomb[lane] = bi;
  }
  __syncthreads();

  // ---- gather winning codebook row, write in (b,c,h,w) layout.
  // lane sweeps spatial (contiguous) -> coalesced stores; wave splits c.
  const int idx = bcomb[lane];
  const float* __restrict__ eq = e + idx * HD;
  #pragma unroll
  for (int i = 0; i < 8; ++i) {
    const int c = w * 8 + i;
    out[xbase + (size_t)c * HW + lane] = eq[c];
  }
}

extern "C" void kernel_launch(void* const* d_in, const int* in_sizes, int n_in,
                              void* d_out, int out_size, void* d_ws, size_t ws_size,
                              hipStream_t stream) {
  const float* x = (const float*)d_in[0];   // (64, 64, 32, 32) fp32
  const float* e = (const float*)d_in[1];   // (512, 64) fp32
  float* ep  = (float*)d_ws;                // 512*64 floats packed -2*e
  float* esq = ep + NE * HD;                // 512 floats
  float* out = (float*)d_out;               // (64, 64, 32, 32) fp32

  vq_prep_kernel<<<72, 64, 0, stream>>>(e, ep, esq);
  vq_main_kernel<<<1024, 512, 0, stream>>>(x, ep, esq, e, out);
}

// Round 6
// 143.053 us; speedup vs baseline: 1.1976x; 1.1976x over previous
//
#include <hip/hip_runtime.h>

#define HD 64       // HIDDEN_DIM
#define NE 512      // N_EMBEDS
#define HW 1024     // 32*32 spatial positions per batch image

// ---------------------------------------------------------------------------
// Prep (130 blocks x 256):
//  blk 0..127 : epT[c][k] = -2 * e[k][c]   (transposed, code-major rows)
//               -2 fold is bit-exact (pow2 scaling commutes with fp32
//               rounding through the fma chain). Verified R3-R5.
//  blk 128/129: esq[k] = np.sum(e[k]*e[k]), numpy pairwise-8 order, no
//               contraction. Verified absmax==0.0 R1-R5.
// ---------------------------------------------------------------------------
__global__ __launch_bounds__(256) void vq_prep_kernel(const float* __restrict__ e,
                                                      float* __restrict__ epT,
                                                      float* __restrict__ esq) {
  const int blk = blockIdx.x;
  if (blk < 128) {
    const int t = blk * 256 + threadIdx.x;     // 0..32767
    const int c = t >> 9, k = t & 511;
    epT[t] = -2.0f * e[k * HD + c];
  } else {
    const int k = (blk - 128) * 256 + threadIdx.x;   // 0..511
    const float4* __restrict__ rowv = reinterpret_cast<const float4*>(e + k * HD);
    float row[HD];
    #pragma unroll
    for (int i = 0; i < 16; ++i) {
      const float4 v = rowv[i];
      row[4 * i + 0] = v.x; row[4 * i + 1] = v.y;
      row[4 * i + 2] = v.z; row[4 * i + 3] = v.w;
    }
    float result;
    {
      #pragma clang fp contract(off)
      float r[8];
      #pragma unroll
      for (int j = 0; j < 8; ++j) r[j] = row[j] * row[j];
      #pragma unroll
      for (int i = 8; i < HD; i += 8) {
        #pragma unroll
        for (int j = 0; j < 8; ++j) r[j] = r[j] + row[i + j] * row[i + j];
      }
      result = ((r[0] + r[1]) + (r[2] + r[3])) + ((r[4] + r[5]) + (r[6] + r[7]));
    }
    esq[k] = result;
  }
}

// ---------------------------------------------------------------------------
// Main R6: 1024 blocks x 256 (4 waves). Block = 64 positions, all 512 codes.
// Wave w: codes [128w, 128w+128). Lane = (p = lane&15, q = lane>>4):
// REGISTER TILE of 4 positions (4p..4p+3) x 8 codes, acc[4][8] in VGPRs.
// Lane's 32 codes are the CONTIGUOUS range [128w+32q, +32), scanned in 4
// ascending 8-code passes -> global ascending-k, first-index-wins preserved
// (codes interleaved across slots would break exact-tie behavior; dist values
// ~64 with ulp 7.6e-6 over a ~5e-3 spread make exact ties likely).
//
// Per c-step: 1 ds_read_b128 (x, 2 dwords/bank = conflict-free) +
// 2 global_load_dwordx4 (e, 16-way same-address -> 1 request) + 32 v_fmac.
// Loads:FMA = 3:32 vs R3's ~1:8 -- the structural fix for the ~10k extra
// VALU inst/wave R3 showed. (256,4): VGPR cap 128, est ~90 live, no spill
// (R4/R5's 64-cap spill showed as WRITE_SIZE 95 MB; must stay 16.4 MB).
// ---------------------------------------------------------------------------
__global__ __launch_bounds__(256, 4) void vq_main_kernel(const float* __restrict__ x,
                                                         const float* __restrict__ epT,
                                                         const float* __restrict__ esq,
                                                         const float* __restrict__ e,
                                                         float* __restrict__ out) {
  __shared__ float xs[HD * 64];      // [c][pos] 16 KB
  __shared__ float xsq[64];
  __shared__ float smin[16][64];     // [slot = 4w+q][pos]
  __shared__ int   sidx[16][64];
  __shared__ int   bcomb[64];

  const int t    = threadIdx.x;
  const int lane = t & 63;
  const int w    = t >> 6;                      // 0..3
  const int blk  = blockIdx.x;                  // 1024
  const int b    = blk >> 4;
  const int s0   = (blk & 15) << 6;
  const size_t xbase = (size_t)b * (HD * HW) + s0;

  // ---- stage x into LDS [c][pos]: wave w loads c in [16w,16w+16)
  #pragma unroll
  for (int i = 0; i < 16; ++i) {
    const int c = w * 16 + i;
    xs[c * 64 + lane] = x[xbase + (size_t)c * HW + lane];
  }
  __syncthreads();

  // ---- xsq[pos] by wave 0: numpy pairwise-8, no contraction (bit-exact)
  if (w == 0) {
    #pragma clang fp contract(off)
    float r[8];
    #pragma unroll
    for (int j = 0; j < 8; ++j) {
      const float v = xs[j * 64 + lane];
      r[j] = v * v;
    }
    #pragma unroll
    for (int i = 8; i < HD; i += 8) {
      #pragma unroll
      for (int j = 0; j < 8; ++j) {
        const float v = xs[(i + j) * 64 + lane];
        r[j] = r[j] + v * v;
      }
    }
    xsq[lane] = ((r[0] + r[1]) + (r[2] + r[3])) + ((r[4] + r[5]) + (r[6] + r[7]));
  }
  __syncthreads();

  const int p = lane & 15;           // position group: positions 4p..4p+3
  const int q = lane >> 4;           // code slot within wave

  // this lane's 4 xsq values (LDS b128, 16B aligned)
  const float4 xq4 = *reinterpret_cast<const float4*>(&xsq[4 * p]);
  const float xq[4] = {xq4.x, xq4.y, xq4.z, xq4.w};

  float bestd[4] = {__builtin_inff(), __builtin_inff(), __builtin_inff(), __builtin_inff()};
  int   besti[4] = {0, 0, 0, 0};

  const int kslot = (w << 5 << 2) + (q << 5);   // 128w + 32q : lane's code range base

  #pragma unroll 1
  for (int pass = 0; pass < 4; ++pass) {
    const int kbase = kslot + (pass << 3);      // ascending within slot
    const float* __restrict__ pe = epT + kbase; // row stride NE floats

    float a[4][8];
    #pragma unroll
    for (int pi = 0; pi < 4; ++pi)
      #pragma unroll
      for (int j = 0; j < 8; ++j) a[pi][j] = 0.f;

    #pragma unroll 2
    for (int c = 0; c < HD; ++c) {
      const float4 xv = *reinterpret_cast<const float4*>(&xs[c * 64 + 4 * p]); // ds_read_b128
      const float4 e0 = *reinterpret_cast<const float4*>(pe + (size_t)c * NE);
      const float4 e1 = *reinterpret_cast<const float4*>(pe + (size_t)c * NE + 4);
      const float xr[4] = {xv.x, xv.y, xv.z, xv.w};
      const float er[8] = {e0.x, e0.y, e0.z, e0.w, e1.x, e1.y, e1.z, e1.w};
      #pragma unroll
      for (int pi = 0; pi < 4; ++pi)
        #pragma unroll
        for (int j = 0; j < 8; ++j)
          a[pi][j] = fmaf(xr[pi], er[j], a[pi][j]);  // sequential-c chain == BLAS order; a = -2*cross
    }

    // dist + argmin for this 8-code group (ascending j; strict < first-wins)
    const float4 es0 = *reinterpret_cast<const float4*>(esq + kbase);
    const float4 es1 = *reinterpret_cast<const float4*>(esq + kbase + 4);
    const float es[8] = {es0.x, es0.y, es0.z, es0.w, es1.x, es1.y, es1.z, es1.w};
    #pragma unroll
    for (int pi = 0; pi < 4; ++pi) {
      #pragma unroll
      for (int j = 0; j < 8; ++j) {
        const float d = (xq[pi] + es[j]) + a[pi][j];  // == (xsq+esq) - 2*cross, bit-exact
        if (d < bestd[pi]) { bestd[pi] = d; besti[pi] = kbase + j; }
      }
    }
  }

  // ---- combine: slot s = 4w+q covers contiguous codes [32s, 32s+32);
  // ascending-s scan with strict < == global first-index-wins.
  *reinterpret_cast<float4*>(&smin[w * 4 + q][4 * p]) =
      make_float4(bestd[0], bestd[1], bestd[2], bestd[3]);
  *reinterpret_cast<int4*>(&sidx[w * 4 + q][4 * p]) =
      make_int4(besti[0], besti[1], besti[2], besti[3]);
  __syncthreads();
  if (w == 0) {
    float bd = smin[0][lane];
    int   bi = sidx[0][lane];
    #pragma unroll
    for (int s = 1; s < 16; ++s) {
      const float d = smin[s][lane];
      if (d < bd) { bd = d; bi = sidx[s][lane]; }
    }
    bcomb[lane] = bi;
  }
  __syncthreads();

  // ---- gather winning codebook row (L2-hot), coalesced store
  const int idx = bcomb[lane];
  const float* __restrict__ eq = e + idx * HD;
  #pragma unroll
  for (int i = 0; i < 16; ++i) {
    const int c = w * 16 + i;
    out[xbase + (size_t)c * HW + lane] = eq[c];
  }
}

extern "C" void kernel_launch(void* const* d_in, const int* in_sizes, int n_in,
                              void* d_out, int out_size, void* d_ws, size_t ws_size,
                              hipStream_t stream) {
  const float* x = (const float*)d_in[0];   // (64, 64, 32, 32) fp32
  const float* e = (const float*)d_in[1];   // (512, 64) fp32
  float* epT = (float*)d_ws;                // 64*512 floats: -2*e transposed
  float* esq = epT + HD * NE;               // 512 floats
  float* out = (float*)d_out;

  vq_prep_kernel<<<130, 256, 0, stream>>>(e, epT, esq);
  vq_main_kernel<<<1024, 256, 0, stream>>>(x, epT, esq, e, out);
}

// Round 7
// 142.468 us; speedup vs baseline: 1.2026x; 1.0041x over previous
//
#include <hip/hip_runtime.h>

#define HD 64       // HIDDEN_DIM
#define NE 512      // N_EMBEDS
#define HW 1024     // 32*32 spatial positions per batch image

// ---------------------------------------------------------------------------
// Prep (130 blocks x 256):
//  blk 0..127 : epT[c][k] = -2 * e[k][c]   (transposed, code-major rows)
//               -2 fold is bit-exact (pow2 scaling commutes with fp32
//               rounding through the fma chain). Verified R3-R6.
//  blk 128/129: esq[k] = np.sum(e[k]*e[k]), numpy pairwise-8 order, no
//               contraction. Verified absmax==0.0 R1-R6.
// ---------------------------------------------------------------------------
__global__ __launch_bounds__(256) void vq_prep_kernel(const float* __restrict__ e,
                                                      float* __restrict__ epT,
                                                      float* __restrict__ esq) {
  const int blk = blockIdx.x;
  if (blk < 128) {
    const int t = blk * 256 + threadIdx.x;     // 0..32767
    const int c = t >> 9, k = t & 511;
    epT[t] = -2.0f * e[k * HD + c];
  } else {
    const int k = (blk - 128) * 256 + threadIdx.x;   // 0..511
    const float4* __restrict__ rowv = reinterpret_cast<const float4*>(e + k * HD);
    float row[HD];
    #pragma unroll
    for (int i = 0; i < 16; ++i) {
      const float4 v = rowv[i];
      row[4 * i + 0] = v.x; row[4 * i + 1] = v.y;
      row[4 * i + 2] = v.z; row[4 * i + 3] = v.w;
    }
    float result;
    {
      #pragma clang fp contract(off)
      float r[8];
      #pragma unroll
      for (int j = 0; j < 8; ++j) r[j] = row[j] * row[j];
      #pragma unroll
      for (int i = 8; i < HD; i += 8) {
        #pragma unroll
        for (int j = 0; j < 8; ++j) r[j] = r[j] + row[i + j] * row[i + j];
      }
      result = ((r[0] + r[1]) + (r[2] + r[3])) + ((r[4] + r[5]) + (r[6] + r[7]));
    }
    esq[k] = result;
  }
}

// ---------------------------------------------------------------------------
// Main R7: 2048 blocks x 256 (4 waves). Block = 32 positions x all 512 codes
// (R6 halved: R6's 4-blocks/CU grid left the latency-bound inner loop with
// only 16 waves/CU -> VALUBusy 44.5%, 50% stall on e-load vmcnt. 2048 blocks
// -> 8 blocks/CU = 32 waves/CU at VGPR<=56).
// Wave w: codes [128w,128w+128). Lane = (p=lane&7, q=lane>>3):
// register tile 4 positions (4p..4p+3) x 8 codes; slot q covers contiguous
// codes [128w+16q,+16) in 2 ascending passes -> combine over slots s=8w+q
// scans codes 16s ascending => np.argmin first-index-wins preserved.
// Per c-step: 1 ds_read_b128 (broadcast x8, conflict-free) +
// 2 global_load_dwordx4 (e, 8-way same-address) + 32 v_fmac.
// ---------------------------------------------------------------------------
__global__ __launch_bounds__(256, 4) void vq_main_kernel(const float* __restrict__ x,
                                                         const float* __restrict__ epT,
                                                         const float* __restrict__ esq,
                                                         const float* __restrict__ e,
                                                         float* __restrict__ out) {
  __shared__ float xs[HD * 32];      // [c][pos] 8 KB
  __shared__ float xsq[32];
  __shared__ float smin[32][32];     // [slot = 8w+q][pos]
  __shared__ int   sidx[32][32];
  __shared__ int   bcomb[32];

  const int t    = threadIdx.x;
  const int lane = t & 63;
  const int w    = t >> 6;                      // 0..3
  const int blk  = blockIdx.x;                  // 2048
  const int b    = blk >> 5;                    // batch
  const int s0   = (blk & 31) << 5;             // spatial chunk base (32 pos)
  const size_t xbase = (size_t)b * (HD * HW) + s0;

  // ---- stage x into LDS [c][pos]: 2048 floats, 8 iters of 256 threads
  {
    const int pos = t & 31, crow = t >> 5;      // crow 0..7
    #pragma unroll
    for (int i = 0; i < 8; ++i) {
      const int c = crow + 8 * i;
      xs[c * 32 + pos] = x[xbase + (size_t)c * HW + pos];
    }
  }
  __syncthreads();

  // ---- xsq[pos]: numpy pairwise-8, no contraction (bit-exact)
  if (t < 32) {
    #pragma clang fp contract(off)
    float r[8];
    #pragma unroll
    for (int j = 0; j < 8; ++j) {
      const float v = xs[j * 32 + t];
      r[j] = v * v;
    }
    #pragma unroll
    for (int i = 8; i < HD; i += 8) {
      #pragma unroll
      for (int j = 0; j < 8; ++j) {
        const float v = xs[(i + j) * 32 + t];
        r[j] = r[j] + v * v;
      }
    }
    xsq[t] = ((r[0] + r[1]) + (r[2] + r[3])) + ((r[4] + r[5]) + (r[6] + r[7]));
  }
  __syncthreads();

  const int p = lane & 7;            // position group: positions 4p..4p+3
  const int q = lane >> 3;           // code slot within wave (0..7)

  const float4 xq4 = *reinterpret_cast<const float4*>(&xsq[4 * p]);
  const float xq[4] = {xq4.x, xq4.y, xq4.z, xq4.w};

  float bestd[4] = {__builtin_inff(), __builtin_inff(), __builtin_inff(), __builtin_inff()};
  int   besti[4] = {0, 0, 0, 0};

  const int kslot = (w << 7) + (q << 4);        // 128w + 16q

  #pragma unroll 1
  for (int pass = 0; pass < 2; ++pass) {
    const int kbase = kslot + (pass << 3);      // ascending within slot
    const float* __restrict__ pe = epT + kbase; // row stride NE floats

    float a[4][8];
    #pragma unroll
    for (int pi = 0; pi < 4; ++pi)
      #pragma unroll
      for (int j = 0; j < 8; ++j) a[pi][j] = 0.f;

    #pragma unroll 2
    for (int c = 0; c < HD; ++c) {
      const float4 xv = *reinterpret_cast<const float4*>(&xs[c * 32 + 4 * p]); // ds_read_b128
      const float4 e0 = *reinterpret_cast<const float4*>(pe + (size_t)c * NE);
      const float4 e1 = *reinterpret_cast<const float4*>(pe + (size_t)c * NE + 4);
      const float xr[4] = {xv.x, xv.y, xv.z, xv.w};
      const float er[8] = {e0.x, e0.y, e0.z, e0.w, e1.x, e1.y, e1.z, e1.w};
      #pragma unroll
      for (int pi = 0; pi < 4; ++pi)
        #pragma unroll
        for (int j = 0; j < 8; ++j)
          a[pi][j] = fmaf(xr[pi], er[j], a[pi][j]);  // sequential-c chain == BLAS order
    }

    const float4 es0 = *reinterpret_cast<const float4*>(esq + kbase);
    const float4 es1 = *reinterpret_cast<const float4*>(esq + kbase + 4);
    const float es[8] = {es0.x, es0.y, es0.z, es0.w, es1.x, es1.y, es1.z, es1.w};
    #pragma unroll
    for (int pi = 0; pi < 4; ++pi) {
      #pragma unroll
      for (int j = 0; j < 8; ++j) {
        const float d = (xq[pi] + es[j]) + a[pi][j];  // == (xsq+esq) - 2*cross, bit-exact
        if (d < bestd[pi]) { bestd[pi] = d; besti[pi] = kbase + j; }
      }
    }
  }

  // ---- combine: slot s = 8w+q covers contiguous codes [16s,16s+16);
  // ascending-s scan with strict < == global first-index-wins.
  *reinterpret_cast<float4*>(&smin[w * 8 + q][4 * p]) =
      make_float4(bestd[0], bestd[1], bestd[2], bestd[3]);
  *reinterpret_cast<int4*>(&sidx[w * 8 + q][4 * p]) =
      make_int4(besti[0], besti[1], besti[2], besti[3]);
  __syncthreads();
  if (t < 32) {
    float bd = smin[0][t];
    int   bi = sidx[0][t];
    #pragma unroll
    for (int s = 1; s < 32; ++s) {
      const float d = smin[s][t];
      if (d < bd) { bd = d; bi = sidx[s][t]; }
    }
    bcomb[t] = bi;
  }
  __syncthreads();

  // ---- gather winning codebook row (L2-hot), coalesced 32-wide stores
  {
    const int pos = t & 31, crow = t >> 5;
    const int idx = bcomb[pos];
    const float* __restrict__ eq = e + idx * HD;
    #pragma unroll
    for (int i = 0; i < 8; ++i) {
      const int c = crow + 8 * i;
      out[xbase + (size_t)c * HW + pos] = eq[c];
    }
  }
}

extern "C" void kernel_launch(void* const* d_in, const int* in_sizes, int n_in,
                              void* d_out, int out_size, void* d_ws, size_t ws_size,
                              hipStream_t stream) {
  const float* x = (const float*)d_in[0];   // (64, 64, 32, 32) fp32
  const float* e = (const float*)d_in[1];   // (512, 64) fp32
  float* epT = (float*)d_ws;                // 64*512 floats: -2*e transposed
  float* esq = epT + HD * NE;               // 512 floats
  float* out = (float*)d_out;

  vq_prep_kernel<<<130, 256, 0, stream>>>(e, epT, esq);
  vq_main_kernel<<<2048, 256, 0, stream>>>(x, epT, esq, e, out);
}

// Round 8
// 133.524 us; speedup vs baseline: 1.2831x; 1.0670x over previous
//
#include <hip/hip_runtime.h>

#define HD 64       // HIDDEN_DIM
#define NE 512      // N_EMBEDS
#define HW 1024     // 32*32 spatial positions per batch image

// ---------------------------------------------------------------------------
// Prep (130 blocks x 256):
//  blk 0..127 : epT[c][k] = -2 * e[k][c]   (transposed, code-major rows)
//               -2 fold is bit-exact (pow2 scaling commutes with fp32
//               rounding through the fma chain). Verified R3-R7.
//  blk 128/129: esq[k] = np.sum(e[k]*e[k]), numpy pairwise-8 order, no
//               contraction. Verified absmax==0.0 R1-R7.
// ---------------------------------------------------------------------------
__global__ __launch_bounds__(256) void vq_prep_kernel(const float* __restrict__ e,
                                                      float* __restrict__ epT,
                                                      float* __restrict__ esq) {
  const int blk = blockIdx.x;
  if (blk < 128) {
    const int t = blk * 256 + threadIdx.x;     // 0..32767
    const int c = t >> 9, k = t & 511;
    epT[t] = -2.0f * e[k * HD + c];
  } else {
    const int k = (blk - 128) * 256 + threadIdx.x;   // 0..511
    const float4* __restrict__ rowv = reinterpret_cast<const float4*>(e + k * HD);
    float row[HD];
    #pragma unroll
    for (int i = 0; i < 16; ++i) {
      const float4 v = rowv[i];
      row[4 * i + 0] = v.x; row[4 * i + 1] = v.y;
      row[4 * i + 2] = v.z; row[4 * i + 3] = v.w;
    }
    float result;
    {
      #pragma clang fp contract(off)
      float r[8];
      #pragma unroll
      for (int j = 0; j < 8; ++j) r[j] = row[j] * row[j];
      #pragma unroll
      for (int i = 8; i < HD; i += 8) {
        #pragma unroll
        for (int j = 0; j < 8; ++j) r[j] = r[j] + row[i + j] * row[i + j];
      }
      result = ((r[0] + r[1]) + (r[2] + r[3])) + ((r[4] + r[5]) + (r[6] + r[7]));
    }
    esq[k] = result;
  }
}

// ---------------------------------------------------------------------------
// Main R8: 2048 blocks x 512 (8 waves). Block = 32 positions x all 512 codes.
//
// R6/R7 post-mortem: VALUBusy pinned at 45% independent of wave count ->
// per-CU VMEM-pipe throughput bound (8192 e-load wave-instrs/CU, 8-way
// same-address duplicated, ~16 cyc each ~ 55 us). Fix: stage epT through
// LDS in 8 chunks of 16 KB with per-lane DISTINCT cooperative loads
// (software-pipelined: prefetch ch+1 in regs during compute of ch).
// e-VMEM instrs/CU drop 8x; compute reads come from LDS (3x ds_read_b128
// per c-step, same-address lanes broadcast -> < 64 FMA issue cyc) ->
// VALU becomes the binding pipe.
//
// Geometry: wave w: wc=w&3 code-quarter, wp=w>>2 pos-half. Lane: p=lane&3,
// q=lane>>2: 4 positions (posb=16wp+4p ..+3) x 8 contiguous codes
// (kb=128wc+8q ..+7). acc[4][8] persists across chunks (c = 0..63 ascending
// sequential fmaf chain, identical order to R7 -> bit-exact); argmin once at
// the end. Slot s = 16wc+q covers codes [8s,8s+8): ascending-s scan with
// strict < == np.argmin first-index-wins. smin/sidx overlay es after the
// final compute barrier (LDS budget: 8+16+0.3 KB).
// ---------------------------------------------------------------------------
__global__ __launch_bounds__(512, 4) void vq_main_kernel(const float* __restrict__ x,
                                                         const float* __restrict__ epT,
                                                         const float* __restrict__ esq,
                                                         const float* __restrict__ e,
                                                         float* __restrict__ out) {
  __shared__ float xs[HD * 32];        // 8 KB   [c][pos]
  __shared__ float es[8 * NE];         // 16 KB  chunk [cc][k]; overlaid by smin/sidx
  __shared__ float xsq[32];
  __shared__ int   bcomb[32];

  float* smin = es;                    // [64][32] floats (8 KB)  -- after last compute
  int*   sidx = (int*)(es + 64 * 32);  // [64][32] ints   (8 KB)

  const int t    = threadIdx.x;
  const int lane = t & 63;
  const int w    = t >> 6;             // 0..7
  const int wc   = w & 3;              // code quarter
  const int wp   = w >> 2;             // pos half
  const int p    = lane & 3;           // pos group
  const int q    = lane >> 2;          // 0..15 code slot
  const int posb = wp * 16 + p * 4;    // lane's 4 positions
  const int kb   = wc * 128 + q * 8;   // lane's 8 codes

  const int blk = blockIdx.x;          // 2048
  const int b   = blk >> 5;
  const int s0  = (blk & 31) << 5;
  const size_t xbase = (size_t)b * (HD * HW) + s0;

  // ---- stage x into LDS [c][pos] (512 threads x 4 floats, coalesced)
  {
    const int pos = t & 31, cr = t >> 5;        // cr 0..15
    #pragma unroll
    for (int i = 0; i < 4; ++i) {
      const int c = cr + 16 * i;
      xs[c * 32 + pos] = x[xbase + (size_t)c * HW + pos];
    }
  }
  __syncthreads();

  // ---- xsq[pos]: numpy pairwise-8, no contraction (bit-exact)
  if (t < 32) {
    #pragma clang fp contract(off)
    float r[8];
    #pragma unroll
    for (int j = 0; j < 8; ++j) {
      const float v = xs[j * 32 + t];
      r[j] = v * v;
    }
    #pragma unroll
    for (int i = 8; i < HD; i += 8) {
      #pragma unroll
      for (int j = 0; j < 8; ++j) {
        const float v = xs[(i + j) * 32 + t];
        r[j] = r[j] + v * v;
      }
    }
    xsq[t] = ((r[0] + r[1]) + (r[2] + r[3])) + ((r[4] + r[5]) + (r[6] + r[7]));
  }

  // ---- chunked, software-pipelined e-staging + accumulate
  const float4* __restrict__ esrc = reinterpret_cast<const float4*>(epT); // 8192 float4
  float4 v0 = esrc[t];                 // chunk 0 prefetch (distinct 16B/lane)
  float4 v1 = esrc[t + 512];

  float acc[4][8];
  #pragma unroll
  for (int pi = 0; pi < 4; ++pi)
    #pragma unroll
    for (int j = 0; j < 8; ++j) acc[pi][j] = 0.f;

  #pragma unroll 1
  for (int ch = 0; ch < 8; ++ch) {
    __syncthreads();                   // previous chunk fully consumed
    reinterpret_cast<float4*>(es)[t]       = v0;
    reinterpret_cast<float4*>(es)[t + 512] = v1;
    if (ch < 7) {                      // prefetch next chunk during compute
      v0 = esrc[(ch + 1) * 1024 + t];
      v1 = esrc[(ch + 1) * 1024 + t + 512];
    }
    __syncthreads();                   // es ready

    #pragma unroll
    for (int cc = 0; cc < 8; ++cc) {
      const int c = ch * 8 + cc;
      const float4 xv = *reinterpret_cast<const float4*>(&xs[c * 32 + posb]);
      const float4 e0 = *reinterpret_cast<const float4*>(&es[cc * NE + kb]);
      const float4 e1 = *reinterpret_cast<const float4*>(&es[cc * NE + kb + 4]);
      const float xr[4] = {xv.x, xv.y, xv.z, xv.w};
      const float er[8] = {e0.x, e0.y, e0.z, e0.w, e1.x, e1.y, e1.z, e1.w};
      #pragma unroll
      for (int pi = 0; pi < 4; ++pi)
        #pragma unroll
        for (int j = 0; j < 8; ++j)
          acc[pi][j] = fmaf(xr[pi], er[j], acc[pi][j]);  // c-ascending chain == BLAS order
    }
  }
  __syncthreads();                     // es done; safe to overlay smin/sidx

  // ---- dist + per-lane argmin (once; acc == -2*cross complete)
  const float4 xq4 = *reinterpret_cast<const float4*>(&xsq[posb]);
  const float xqv[4] = {xq4.x, xq4.y, xq4.z, xq4.w};
  const float4 eq0 = *reinterpret_cast<const float4*>(esq + kb);
  const float4 eq1 = *reinterpret_cast<const float4*>(esq + kb + 4);
  const float esv[8] = {eq0.x, eq0.y, eq0.z, eq0.w, eq1.x, eq1.y, eq1.z, eq1.w};

  float bestd[4] = {__builtin_inff(), __builtin_inff(), __builtin_inff(), __builtin_inff()};
  int   besti[4] = {0, 0, 0, 0};
  #pragma unroll
  for (int pi = 0; pi < 4; ++pi) {
    #pragma unroll
    for (int j = 0; j < 8; ++j) {     // ascending j: first-index-wins
      const float d = (xqv[pi] + esv[j]) + acc[pi][j];  // == (xsq+esq) - 2*cross
      if (d < bestd[pi]) { bestd[pi] = d; besti[pi] = kb + j; }
    }
  }

  // ---- combine: slot s = 16wc+q covers codes [8s,8s+8); ascending-s scan
  const int s = wc * 16 + q;
  *reinterpret_cast<float4*>(&smin[s * 32 + posb]) =
      make_float4(bestd[0], bestd[1], bestd[2], bestd[3]);
  *reinterpret_cast<int4*>(&sidx[s * 32 + posb]) =
      make_int4(besti[0], besti[1], besti[2], besti[3]);
  __syncthreads();
  if (t < 32) {
    float bd = smin[t];
    int   bi = sidx[t];
    #pragma unroll
    for (int ss = 1; ss < 64; ++ss) {
      const float d = smin[ss * 32 + t];
      if (d < bd) { bd = d; bi = sidx[ss * 32 + t]; }
    }
    bcomb[t] = bi;
  }
  __syncthreads();

  // ---- gather winning codebook row (L2-hot), coalesced stores
  {
    const int pos = t & 31, cr = t >> 5;
    const int idx = bcomb[pos];
    const float* __restrict__ eq = e + idx * HD;
    #pragma unroll
    for (int i = 0; i < 4; ++i) {
      const int c = cr + 16 * i;
      out[xbase + (size_t)c * HW + pos] = eq[c];
    }
  }
}

extern "C" void kernel_launch(void* const* d_in, const int* in_sizes, int n_in,
                              void* d_out, int out_size, void* d_ws, size_t ws_size,
                              hipStream_t stream) {
  const float* x = (const float*)d_in[0];   // (64, 64, 32, 32) fp32
  const float* e = (const float*)d_in[1];   // (512, 64) fp32
  float* epT = (float*)d_ws;                // 64*512 floats: -2*e transposed
  float* esq = epT + HD * NE;               // 512 floats
  float* out = (float*)d_out;

  vq_prep_kernel<<<130, 256, 0, stream>>>(e, epT, esq);
  vq_main_kernel<<<2048, 512, 0, stream>>>(x, epT, esq, e, out);
}